// Round 1
// baseline (466.213 us; speedup 1.0000x reference)
//
#include <hip/hip_runtime.h>

// Problem: x (4096, 2, 1024) fp32.
//   P_i = x[i,0,:], A_j = x[i,1,:]
//   out[0] = nloss = 1.0 exactly (exp(t - stop_grad(t)) == exp(0))
//   out[1] = prec1 = 100 * mean(argmax_j sim[i,j] == i)
//   argmax_j sim[i,j] == argmax_j dot(P_i, A_j) * inv_norm(A_j)  (row norm > 0 constant)

#define NROWS 4096
#define DDIM  1024
#define XSTR  2048   // row stride of x in floats (2*1024)

#define BM 128
#define BN 128
#define BK 16

__device__ __forceinline__ unsigned int fkey(float f) {
    unsigned int u = __float_as_uint(f);
    return (u & 0x80000000u) ? ~u : (u | 0x80000000u);
}

__device__ __forceinline__ unsigned long long shfl_xor_u64(unsigned long long v, int m) {
    unsigned int lo = (unsigned int)v;
    unsigned int hi = (unsigned int)(v >> 32);
    lo = __shfl_xor(lo, m, 64);
    hi = __shfl_xor(hi, m, 64);
    return ((unsigned long long)hi << 32) | lo;
}

// Kernel A: anchor inverse norms + zero the packed argmax buffer.
// grid 1024 x 256 threads: one wave per anchor row.
__global__ __launch_bounds__(256) void norms_kernel(const float* __restrict__ x,
                                                    float* __restrict__ inv_an,
                                                    unsigned long long* __restrict__ packed) {
    int gid  = blockIdx.x * 256 + threadIdx.x;
    int j    = gid >> 6;           // wave id = anchor row
    int lane = threadIdx.x & 63;

    if (gid < NROWS) packed[gid] = 0ULL;   // identity for packed-max

    const float4* a = (const float4*)(x + (size_t)j * XSTR + DDIM);
    float s = 0.0f;
#pragma unroll
    for (int i = 0; i < 4; ++i) {
        float4 v = a[lane + i * 64];
        s += v.x * v.x + v.y * v.y + v.z * v.z + v.w * v.w;
    }
#pragma unroll
    for (int off = 32; off > 0; off >>= 1) s += __shfl_down(s, off, 64);
    if (lane == 0) inv_an[j] = 1.0f / sqrtf(s);
}

// Kernel B: fused 4096x4096x1024 fp32 matmul + per-row argmax via packed atomicMax.
// grid (32 row-tiles, 32 col-tiles), 256 threads, 8x8 micro-tile.
__global__ __launch_bounds__(256) void gemm_argmax_kernel(const float* __restrict__ x,
                                                          const float* __restrict__ inv_an,
                                                          unsigned long long* __restrict__ packed) {
    __shared__ __align__(16) float Pt[BK][BM];   // [k][row]
    __shared__ __align__(16) float At[BK][BN];   // [k][col]

    const int r0 = blockIdx.x * BM;
    const int c0 = blockIdx.y * BN;

    const int t   = threadIdx.x;
    const int tx  = t & 15;        // col group
    const int ty  = t >> 4;        // row group
    const int srow = t >> 1;       // staging row/col index 0..127
    const int skq  = (t & 1) * 8;  // staging k offset 0 or 8

    float acc[8][8];
#pragma unroll
    for (int r = 0; r < 8; ++r)
#pragma unroll
        for (int c = 0; c < 8; ++c) acc[r][c] = 0.0f;

    const float* gp = x + (size_t)(r0 + srow) * XSTR + skq;         // positive rows
    const float* ga = x + (size_t)(c0 + srow) * XSTR + DDIM + skq;  // anchor rows

    for (int k0 = 0; k0 < DDIM; k0 += BK) {
        __syncthreads();
        float4 p0 = *(const float4*)(gp + k0);
        float4 p1 = *(const float4*)(gp + k0 + 4);
        float4 a0 = *(const float4*)(ga + k0);
        float4 a1 = *(const float4*)(ga + k0 + 4);
        Pt[skq + 0][srow] = p0.x; Pt[skq + 1][srow] = p0.y;
        Pt[skq + 2][srow] = p0.z; Pt[skq + 3][srow] = p0.w;
        Pt[skq + 4][srow] = p1.x; Pt[skq + 5][srow] = p1.y;
        Pt[skq + 6][srow] = p1.z; Pt[skq + 7][srow] = p1.w;
        At[skq + 0][srow] = a0.x; At[skq + 1][srow] = a0.y;
        At[skq + 2][srow] = a0.z; At[skq + 3][srow] = a0.w;
        At[skq + 4][srow] = a1.x; At[skq + 5][srow] = a1.y;
        At[skq + 6][srow] = a1.z; At[skq + 7][srow] = a1.w;
        __syncthreads();

#pragma unroll
        for (int kk = 0; kk < BK; ++kk) {
            float pr[8], ar[8];
            *(float4*)&pr[0] = *(const float4*)&Pt[kk][ty * 8];
            *(float4*)&pr[4] = *(const float4*)&Pt[kk][ty * 8 + 4];
            *(float4*)&ar[0] = *(const float4*)&At[kk][tx * 8];
            *(float4*)&ar[4] = *(const float4*)&At[kk][tx * 8 + 4];
#pragma unroll
            for (int r = 0; r < 8; ++r)
#pragma unroll
                for (int c = 0; c < 8; ++c) acc[r][c] += pr[r] * ar[c];
        }
    }

    // Epilogue: scale by inv_an[col], local argmax over this thread's 8 cols,
    // reduce across the 16 tx lanes, then one atomicMax per row.
    float ian[8];
#pragma unroll
    for (int c = 0; c < 8; ++c) ian[c] = inv_an[c0 + tx * 8 + c];

#pragma unroll
    for (int r = 0; r < 8; ++r) {
        int row = r0 + ty * 8 + r;
        unsigned long long best = 0ULL;
#pragma unroll
        for (int c = 0; c < 8; ++c) {
            int col = c0 + tx * 8 + c;
            float v = acc[r][c] * ian[c];
            unsigned long long p =
                ((unsigned long long)fkey(v) << 32) | (unsigned int)(~col);
            best = best > p ? best : p;
        }
#pragma unroll
        for (int m = 1; m <= 8; m <<= 1) {
            unsigned long long o = shfl_xor_u64(best, m);
            best = best > o ? best : o;
        }
        if (tx == 0) atomicMax(&packed[row], best);
    }
}

// Kernel C: count argmax==row, write (nloss=1.0, prec1).
__global__ __launch_bounds__(256) void finalize_kernel(const unsigned long long* __restrict__ packed,
                                                       float* __restrict__ out) {
    __shared__ int cnt_s;
    int t = threadIdx.x;
    if (t == 0) cnt_s = 0;
    __syncthreads();
    int c = 0;
    for (int r = t; r < NROWS; r += 256) {
        unsigned int col = ~(unsigned int)(packed[r] & 0xFFFFFFFFULL);
        c += (col == (unsigned int)r) ? 1 : 0;
    }
#pragma unroll
    for (int off = 32; off > 0; off >>= 1) c += __shfl_down(c, off, 64);
    if ((t & 63) == 0) atomicAdd(&cnt_s, c);
    __syncthreads();
    if (t == 0) {
        out[0] = 1.0f;  // exp(temploss - stop_gradient(temploss)) == 1 exactly
        out[1] = 100.0f * (float)cnt_s / (float)NROWS;
    }
}

extern "C" void kernel_launch(void* const* d_in, const int* in_sizes, int n_in,
                              void* d_out, int out_size, void* d_ws, size_t ws_size,
                              hipStream_t stream) {
    (void)in_sizes; (void)n_in; (void)out_size; (void)ws_size;
    const float* x = (const float*)d_in[0];
    float* out = (float*)d_out;

    float* inv_an = (float*)d_ws;                                            // 4096 floats
    unsigned long long* packed =
        (unsigned long long*)((char*)d_ws + NROWS * sizeof(float));          // 4096 u64

    norms_kernel<<<NROWS / 4, 256, 0, stream>>>(x, inv_an, packed);

    dim3 grid(NROWS / BM, NROWS / BN);
    gemm_argmax_kernel<<<grid, 256, 0, stream>>>(x, inv_an, packed);

    finalize_kernel<<<1, 256, 0, stream>>>(packed, out);
}

// Round 2
// 202.451 us; speedup vs baseline: 2.3028x; 2.3028x over previous
//
#include <hip/hip_runtime.h>

// x (4096, 2, 1024) fp32.  P_i = x[i,0,:], A_j = x[i,1,:]
// out[0] = 1.0 exactly; out[1] = prec1 = 100*mean(argmax_j sim[i,j] == i)
// argmax_j sim[i,j] == argmax_j dot(P_i,A_j)*inv_norm(A_j).
// R2: dot via bf16-split 3-pass MFMA: Phi*Ahi + Phi*Alo + Plo*Ahi.
// Dropped lo*lo term ~1e-7 in sim units vs top-2 gaps ~1e-2 -> safe.

#define NROWS 4096
#define DDIM  1024
#define XSTR  2048

typedef unsigned int u32;
typedef unsigned long long u64;
typedef __attribute__((ext_vector_type(8))) short bf16x8;
typedef __attribute__((ext_vector_type(4))) float f32x4;

#define GLOBAL_AS __attribute__((address_space(1)))
#define LDS_AS    __attribute__((address_space(3)))

__device__ __forceinline__ void async_load16(const void* g, void* l) {
    __builtin_amdgcn_global_load_lds((GLOBAL_AS const u32*)g, (LDS_AS u32*)l, 16, 0, 0);
}

__device__ __forceinline__ unsigned int fkey(float f) {
    unsigned int u = __float_as_uint(f);
    return (u & 0x80000000u) ? ~u : (u | 0x80000000u);
}

__device__ __forceinline__ u64 shfl_xor_u64(u64 v, int m) {
    unsigned int lo = (unsigned int)v;
    unsigned int hi = (unsigned int)(v >> 32);
    lo = __shfl_xor(lo, m, 64);
    hi = __shfl_xor(hi, m, 64);
    return ((u64)hi << 32) | lo;
}

__device__ __forceinline__ unsigned short f2bf(float f) {
    unsigned u = __float_as_uint(f);
    return (unsigned short)((u + 0x7FFFu + ((u >> 16) & 1u)) >> 16);
}

// ---------------- MFMA path ----------------
// Workspace layout (bytes):
#define PHI_OFF 0u
#define PLO_OFF 8388608u
#define AHI_OFF 16777216u
#define ALO_OFF 25165824u
#define INV_OFF 33554432u
#define PCK_OFF 33570816u
#define WS_NEED 33603584u

// Prep: fp32 -> (hi,lo) bf16 split for P and A; anchor inv norms; zero packed.
// grid 1024 x 256: one wave per row.
__global__ __launch_bounds__(256) void prep_kernel(const float* __restrict__ x,
                                                   unsigned short* __restrict__ Phi,
                                                   unsigned short* __restrict__ Plo,
                                                   unsigned short* __restrict__ Ahi,
                                                   unsigned short* __restrict__ Alo,
                                                   float* __restrict__ inv_an,
                                                   u64* __restrict__ packed) {
    int gid  = blockIdx.x * 256 + threadIdx.x;
    int row  = gid >> 6;
    int lane = threadIdx.x & 63;
    if (gid < NROWS) packed[gid] = 0ULL;

    const float4* p = (const float4*)(x + (size_t)row * XSTR);
    const float4* a = (const float4*)(x + (size_t)row * XSTR + DDIM);
    ushort4* phi = (ushort4*)(Phi + (size_t)row * DDIM);
    ushort4* plo = (ushort4*)(Plo + (size_t)row * DDIM);
    ushort4* ahi = (ushort4*)(Ahi + (size_t)row * DDIM);
    ushort4* alo = (ushort4*)(Alo + (size_t)row * DDIM);

    float s = 0.0f;
#pragma unroll
    for (int i = 0; i < 4; ++i) {
        int idx = lane + 64 * i;
        float4 v = p[idx];
        ushort4 h, l;
        {
            float f[4] = {v.x, v.y, v.z, v.w};
            unsigned short hh[4], ll[4];
#pragma unroll
            for (int q = 0; q < 4; ++q) {
                hh[q] = f2bf(f[q]);
                float hf = __uint_as_float(((unsigned)hh[q]) << 16);
                ll[q] = f2bf(f[q] - hf);
            }
            h = make_ushort4(hh[0], hh[1], hh[2], hh[3]);
            l = make_ushort4(ll[0], ll[1], ll[2], ll[3]);
        }
        phi[idx] = h; plo[idx] = l;

        float4 w = a[idx];
        s += w.x * w.x + w.y * w.y + w.z * w.z + w.w * w.w;
        {
            float f[4] = {w.x, w.y, w.z, w.w};
            unsigned short hh[4], ll[4];
#pragma unroll
            for (int q = 0; q < 4; ++q) {
                hh[q] = f2bf(f[q]);
                float hf = __uint_as_float(((unsigned)hh[q]) << 16);
                ll[q] = f2bf(f[q] - hf);
            }
            h = make_ushort4(hh[0], hh[1], hh[2], hh[3]);
            l = make_ushort4(ll[0], ll[1], ll[2], ll[3]);
        }
        ahi[idx] = h; alo[idx] = l;
    }
#pragma unroll
    for (int off = 32; off > 0; off >>= 1) s += __shfl_down(s, off, 64);
    if (lane == 0) inv_an[row] = 1.0f / sqrtf(s);
}

// MFMA GEMM + argmax. 128x128 block tile, 4 waves in 2x2 of 64x64 wave tiles.
// K-chunk = 32. LDS: 4 tiles (Phi,Plo,Ahi,Alo) of 128x32 bf16, chunk-rotated:
// 16B chunk c of row r stored at physical chunk (c + (r>>1)) & 3  -> all
// ds_read_b128 frag loads AND global_load_lds writes are bank-uniform.
__global__ __launch_bounds__(256) void mfma_gemm_argmax(const unsigned short* __restrict__ Phi,
                                                        const unsigned short* __restrict__ Plo,
                                                        const unsigned short* __restrict__ Ahi,
                                                        const unsigned short* __restrict__ Alo,
                                                        const float* __restrict__ inv_an,
                                                        u64* __restrict__ packed) {
    __shared__ __align__(16) unsigned short lds[4 * 4096];  // 4 tiles x 8KB

    const int r0 = blockIdx.x * 128;
    const int c0 = blockIdx.y * 128;
    const int wave = threadIdx.x >> 6;
    const int lane = threadIdx.x & 63;
    const int quad = lane >> 4;
    const int lrow = lane & 15;

    // ---- staging setup: wave w stages tile w ----
    const unsigned short* srcs[4] = {Phi, Plo, Ahi, Alo};
    const unsigned short* src = srcs[wave];
    const int base_row = (wave < 2) ? r0 : c0;
    // s-invariant logical chunk for this lane:
    const int lc = ((lane & 3) - (lane >> 3)) & 3;
    const char* gbase = (const char*)(src + (size_t)(base_row + (lane >> 2)) * DDIM) + lc * 16;
    unsigned short* ltile = lds + wave * 4096;

    // ---- fragment LDS byte offsets (k0-invariant) ----
    const int m0 = (wave & 1) * 64;
    const int n0 = (wave >> 1) * 64;
    int poff[4], aoff[4];
#pragma unroll
    for (int t = 0; t < 4; ++t) {
        int rp = m0 + t * 16 + lrow;
        poff[t] = rp * 64 + (((quad + (rp >> 1)) & 3) * 16);
        int ra = n0 + t * 16 + lrow;
        aoff[t] = ra * 64 + (((quad + (ra >> 1)) & 3) * 16);
    }
    const char* ldsb = (const char*)lds;

    f32x4 acc[4][4];
#pragma unroll
    for (int i = 0; i < 4; ++i)
#pragma unroll
        for (int j = 0; j < 4; ++j) acc[i][j] = (f32x4){0.f, 0.f, 0.f, 0.f};

    float ian[4];
#pragma unroll
    for (int t = 0; t < 4; ++t) ian[t] = inv_an[c0 + n0 + t * 16 + lrow];

    for (int k0 = 0; k0 < DDIM; k0 += 32) {
        __syncthreads();
#pragma unroll
        for (int s = 0; s < 8; ++s)
            async_load16(gbase + (size_t)s * 32768 + k0 * 2, ltile + s * 512);
        __syncthreads();

        bf16x8 ph[4], pl[4], ah[4], al[4];
#pragma unroll
        for (int t = 0; t < 4; ++t) {
            ph[t] = *(const bf16x8*)(ldsb + 0 * 8192 + poff[t]);
            pl[t] = *(const bf16x8*)(ldsb + 1 * 8192 + poff[t]);
            ah[t] = *(const bf16x8*)(ldsb + 2 * 8192 + aoff[t]);
            al[t] = *(const bf16x8*)(ldsb + 3 * 8192 + aoff[t]);
        }
#pragma unroll
        for (int mt = 0; mt < 4; ++mt)
#pragma unroll
            for (int nt = 0; nt < 4; ++nt) {
                acc[mt][nt] = __builtin_amdgcn_mfma_f32_16x16x32_bf16(ph[mt], ah[nt], acc[mt][nt], 0, 0, 0);
                acc[mt][nt] = __builtin_amdgcn_mfma_f32_16x16x32_bf16(ph[mt], al[nt], acc[mt][nt], 0, 0, 0);
                acc[mt][nt] = __builtin_amdgcn_mfma_f32_16x16x32_bf16(pl[mt], ah[nt], acc[mt][nt], 0, 0, 0);
            }
    }

    // ---- epilogue: scale by inv_an[col], per-row argmax, packed atomicMax ----
    // C/D layout: col = c0+n0+nt*16+lrow, row = r0+m0+mt*16+quad*4+reg.
#pragma unroll
    for (int mt = 0; mt < 4; ++mt)
#pragma unroll
        for (int reg = 0; reg < 4; ++reg) {
            int row = r0 + m0 + mt * 16 + quad * 4 + reg;
            u64 best = 0ULL;
#pragma unroll
            for (int nt = 0; nt < 4; ++nt) {
                int col = c0 + n0 + nt * 16 + lrow;
                float v = acc[mt][nt][reg] * ian[nt];
                u64 p = ((u64)fkey(v) << 32) | (unsigned int)(~col);
                best = best > p ? best : p;
            }
#pragma unroll
            for (int m = 1; m <= 8; m <<= 1) {
                u64 o = shfl_xor_u64(best, m);
                best = best > o ? best : o;
            }
            if (lrow == 0) atomicMax(&packed[row], best);
        }
}

// ---------------- fallback fp32 path (proven R1) ----------------
__global__ __launch_bounds__(256) void norms_kernel(const float* __restrict__ x,
                                                    float* __restrict__ inv_an,
                                                    u64* __restrict__ packed) {
    int gid  = blockIdx.x * 256 + threadIdx.x;
    int j    = gid >> 6;
    int lane = threadIdx.x & 63;
    if (gid < NROWS) packed[gid] = 0ULL;
    const float4* a = (const float4*)(x + (size_t)j * XSTR + DDIM);
    float s = 0.0f;
#pragma unroll
    for (int i = 0; i < 4; ++i) {
        float4 v = a[lane + i * 64];
        s += v.x * v.x + v.y * v.y + v.z * v.z + v.w * v.w;
    }
#pragma unroll
    for (int off = 32; off > 0; off >>= 1) s += __shfl_down(s, off, 64);
    if (lane == 0) inv_an[j] = 1.0f / sqrtf(s);
}

__global__ __launch_bounds__(256) void gemm_argmax_kernel(const float* __restrict__ x,
                                                          const float* __restrict__ inv_an,
                                                          u64* __restrict__ packed) {
    __shared__ __align__(16) float Pt[16][128];
    __shared__ __align__(16) float At[16][128];
    const int r0 = blockIdx.x * 128;
    const int c0 = blockIdx.y * 128;
    const int t = threadIdx.x;
    const int tx = t & 15;
    const int ty = t >> 4;
    const int srow = t >> 1;
    const int skq = (t & 1) * 8;
    float acc[8][8];
#pragma unroll
    for (int r = 0; r < 8; ++r)
#pragma unroll
        for (int c = 0; c < 8; ++c) acc[r][c] = 0.0f;
    const float* gp = x + (size_t)(r0 + srow) * XSTR + skq;
    const float* ga = x + (size_t)(c0 + srow) * XSTR + DDIM + skq;
    for (int k0 = 0; k0 < DDIM; k0 += 16) {
        __syncthreads();
        float4 p0 = *(const float4*)(gp + k0);
        float4 p1 = *(const float4*)(gp + k0 + 4);
        float4 a0 = *(const float4*)(ga + k0);
        float4 a1 = *(const float4*)(ga + k0 + 4);
        Pt[skq + 0][srow] = p0.x; Pt[skq + 1][srow] = p0.y;
        Pt[skq + 2][srow] = p0.z; Pt[skq + 3][srow] = p0.w;
        Pt[skq + 4][srow] = p1.x; Pt[skq + 5][srow] = p1.y;
        Pt[skq + 6][srow] = p1.z; Pt[skq + 7][srow] = p1.w;
        At[skq + 0][srow] = a0.x; At[skq + 1][srow] = a0.y;
        At[skq + 2][srow] = a0.z; At[skq + 3][srow] = a0.w;
        At[skq + 4][srow] = a1.x; At[skq + 5][srow] = a1.y;
        At[skq + 6][srow] = a1.z; At[skq + 7][srow] = a1.w;
        __syncthreads();
#pragma unroll
        for (int kk = 0; kk < 16; ++kk) {
            float pr[8], ar[8];
            *(float4*)&pr[0] = *(const float4*)&Pt[kk][ty * 8];
            *(float4*)&pr[4] = *(const float4*)&Pt[kk][ty * 8 + 4];
            *(float4*)&ar[0] = *(const float4*)&At[kk][tx * 8];
            *(float4*)&ar[4] = *(const float4*)&At[kk][tx * 8 + 4];
#pragma unroll
            for (int r = 0; r < 8; ++r)
#pragma unroll
                for (int c = 0; c < 8; ++c) acc[r][c] += pr[r] * ar[c];
        }
    }
    float ian[8];
#pragma unroll
    for (int c = 0; c < 8; ++c) ian[c] = inv_an[c0 + tx * 8 + c];
#pragma unroll
    for (int r = 0; r < 8; ++r) {
        int row = r0 + ty * 8 + r;
        u64 best = 0ULL;
#pragma unroll
        for (int c = 0; c < 8; ++c) {
            int col = c0 + tx * 8 + c;
            float v = acc[r][c] * ian[c];
            u64 p = ((u64)fkey(v) << 32) | (unsigned int)(~col);
            best = best > p ? best : p;
        }
#pragma unroll
        for (int m = 1; m <= 8; m <<= 1) {
            u64 o = shfl_xor_u64(best, m);
            best = best > o ? best : o;
        }
        if (tx == 0) atomicMax(&packed[row], best);
    }
}

// ---------------- finalize ----------------
__global__ __launch_bounds__(256) void finalize_kernel(const u64* __restrict__ packed,
                                                       float* __restrict__ out) {
    __shared__ int cnt_s;
    int t = threadIdx.x;
    if (t == 0) cnt_s = 0;
    __syncthreads();
    int c = 0;
    for (int r = t; r < NROWS; r += 256) {
        unsigned int col = ~(unsigned int)(packed[r] & 0xFFFFFFFFULL);
        c += (col == (unsigned int)r) ? 1 : 0;
    }
#pragma unroll
    for (int off = 32; off > 0; off >>= 1) c += __shfl_down(c, off, 64);
    if ((t & 63) == 0) atomicAdd(&cnt_s, c);
    __syncthreads();
    if (t == 0) {
        out[0] = 1.0f;
        out[1] = 100.0f * (float)cnt_s / (float)NROWS;
    }
}

extern "C" void kernel_launch(void* const* d_in, const int* in_sizes, int n_in,
                              void* d_out, int out_size, void* d_ws, size_t ws_size,
                              hipStream_t stream) {
    (void)in_sizes; (void)n_in; (void)out_size;
    const float* x = (const float*)d_in[0];
    float* out = (float*)d_out;

    if (ws_size >= (size_t)WS_NEED) {
        char* ws = (char*)d_ws;
        unsigned short* Phi = (unsigned short*)(ws + PHI_OFF);
        unsigned short* Plo = (unsigned short*)(ws + PLO_OFF);
        unsigned short* Ahi = (unsigned short*)(ws + AHI_OFF);
        unsigned short* Alo = (unsigned short*)(ws + ALO_OFF);
        float* inv_an = (float*)(ws + INV_OFF);
        u64* packed = (u64*)(ws + PCK_OFF);

        prep_kernel<<<NROWS / 4, 256, 0, stream>>>(x, Phi, Plo, Ahi, Alo, inv_an, packed);
        dim3 grid(NROWS / 128, NROWS / 128);
        mfma_gemm_argmax<<<grid, 256, 0, stream>>>(Phi, Plo, Ahi, Alo, inv_an, packed);
        finalize_kernel<<<1, 256, 0, stream>>>(packed, out);
    } else {
        float* inv_an = (float*)d_ws;
        u64* packed = (u64*)((char*)d_ws + NROWS * sizeof(float));
        norms_kernel<<<NROWS / 4, 256, 0, stream>>>(x, inv_an, packed);
        dim3 grid(NROWS / 128, NROWS / 128);
        gemm_argmax_kernel<<<grid, 256, 0, stream>>>(x, inv_an, packed);
        finalize_kernel<<<1, 256, 0, stream>>>(packed, out);
    }
}

// Round 4
// 188.079 us; speedup vs baseline: 2.4788x; 1.0764x over previous
//
#include <hip/hip_runtime.h>

// x (4096, 2, 1024) fp32.  P_i = x[i,0,:], A_j = x[i,1,:]
// out[0] = 1.0 exactly; out[1] = prec1 = 100*mean(argmax_j sim[i,j] == i)
// argmax_j sim[i,j] == argmax_j dot(P_i,A_j)*inv_norm(A_j).
// R4: R3 with the LDS staging/read mismatch fixed. global_load_lds puts
// lane i's 16B at base+i*16, i.e. (row=l31,khalf=lh) -> byte lh*512+l31*16.
// Fragment read offset must be lh*512+l31*16 (was l31*32+lh*16 -> scrambled).

#define NROWS 4096
#define DDIM  1024
#define XSTR  2048

typedef unsigned int u32;
typedef unsigned long long u64;
typedef __attribute__((ext_vector_type(8))) short bf16x8;
typedef __attribute__((ext_vector_type(16))) float f32x16;

#define GLOBAL_AS __attribute__((address_space(1)))
#define LDS_AS    __attribute__((address_space(3)))

__device__ __forceinline__ void async_load16(const void* g, void* l) {
    __builtin_amdgcn_global_load_lds((GLOBAL_AS const u32*)g, (LDS_AS u32*)l, 16, 0, 0);
}

__device__ __forceinline__ unsigned int fkey(float f) {
    unsigned int u = __float_as_uint(f);
    return (u & 0x80000000u) ? ~u : (u | 0x80000000u);
}

__device__ __forceinline__ u64 shfl_xor_u64(u64 v, int m) {
    unsigned int lo = (unsigned int)v;
    unsigned int hi = (unsigned int)(v >> 32);
    lo = __shfl_xor(lo, m, 64);
    hi = __shfl_xor(hi, m, 64);
    return ((u64)hi << 32) | lo;
}

__device__ __forceinline__ unsigned short f2bf(float f) {
    unsigned u = __float_as_uint(f);
    return (unsigned short)((u + 0x7FFFu + ((u >> 16) & 1u)) >> 16);
}

__device__ __forceinline__ void split4(float4 v, ushort4* h, ushort4* l) {
    float f[4] = {v.x, v.y, v.z, v.w};
    unsigned short hh[4], ll[4];
#pragma unroll
    for (int q = 0; q < 4; ++q) {
        hh[q] = f2bf(f[q]);
        float hf = __uint_as_float(((unsigned)hh[q]) << 16);
        ll[q] = f2bf(f[q] - hf);
    }
    *h = make_ushort4(hh[0], hh[1], hh[2], hh[3]);
    *l = make_ushort4(ll[0], ll[1], ll[2], ll[3]);
}

// Workspace layout (bytes):
#define PHI_OFF 0u
#define PLO_OFF 8388608u
#define AHI_OFF 16777216u
#define ALO_OFF 25165824u
#define INV_OFF 33554432u
#define PCK_OFF 33570816u
#define WS_NEED 33603584u

// Prep: one block per row. Split fp32 -> (hi,lo) bf16 for P and A,
// block-reduce anchor norm, zero packed[row].
__global__ __launch_bounds__(256) void prep_kernel(const float* __restrict__ x,
                                                   unsigned short* __restrict__ Phi,
                                                   unsigned short* __restrict__ Plo,
                                                   unsigned short* __restrict__ Ahi,
                                                   unsigned short* __restrict__ Alo,
                                                   float* __restrict__ inv_an,
                                                   u64* __restrict__ packed) {
    __shared__ float red[4];
    const int b = blockIdx.x;
    const int t = threadIdx.x;

    float4 pv = *(const float4*)(x + (size_t)b * XSTR + t * 4);
    float4 av = *(const float4*)(x + (size_t)b * XSTR + DDIM + t * 4);

    ushort4 h, l;
    split4(pv, &h, &l);
    ((ushort4*)Phi)[(size_t)b * 256 + t] = h;
    ((ushort4*)Plo)[(size_t)b * 256 + t] = l;
    split4(av, &h, &l);
    ((ushort4*)Ahi)[(size_t)b * 256 + t] = h;
    ((ushort4*)Alo)[(size_t)b * 256 + t] = l;

    float s = av.x * av.x + av.y * av.y + av.z * av.z + av.w * av.w;
#pragma unroll
    for (int off = 32; off > 0; off >>= 1) s += __shfl_down(s, off, 64);
    if ((t & 63) == 0) red[t >> 6] = s;
    __syncthreads();
    if (t == 0) {
        inv_an[b] = 1.0f / sqrtf(red[0] + red[1] + red[2] + red[3]);
        packed[b] = 0ULL;
    }
}

// MFMA GEMM + argmax. 256x256 block tile, 4 waves (2x2) of 128x128.
// 32x32x16 bf16 MFMA, BK=16, double-buffered 2x32KB LDS.
// LDS per buffer: array a (Phi,Plo,Ahi,Alo) x rb (8 blocks of 32 rows) x 1KB.
// Within a 1KB segment, (row r, khalf q) lives at byte q*512 + r*16 — the
// order global_load_lds produces (lane i = q*32+r at base+i*16).
__global__ __launch_bounds__(256, 1) void mfma_gemm_argmax(const unsigned short* __restrict__ Phi,
                                                           const unsigned short* __restrict__ Plo,
                                                           const unsigned short* __restrict__ Ahi,
                                                           const unsigned short* __restrict__ Alo,
                                                           const float* __restrict__ inv_an,
                                                           u64* __restrict__ packed) {
    __shared__ __align__(16) unsigned short lds[32768];  // 2 bufs x 16384 ushort (32KB each)

    const int r0 = blockIdx.x * 256;
    const int c0 = blockIdx.y * 256;
    const int wave = threadIdx.x >> 6;
    const int lane = threadIdx.x & 63;
    const int l31 = lane & 31;
    const int lh = lane >> 5;
    const int wm = wave & 1;
    const int wn = wave >> 1;

    // ---- staging: wave w stages array w (8 x 1KB segments per chunk) ----
    const unsigned short* srcs[4] = {Phi, Plo, Ahi, Alo};
    const char* gp[8];
    {
        const unsigned short* src = srcs[wave];
        const int baserow = (wave < 2) ? r0 : c0;
#pragma unroll
        for (int rb = 0; rb < 8; ++rb)
            gp[rb] = (const char*)(src + (size_t)(baserow + rb * 32 + l31) * DDIM) + lh * 16;
    }
    unsigned short* myseg = lds + wave * 4096;  // + buf*16384 + rb*512 (ushort units)

    // frag read offset within an (array, rb) 1KB segment (ushort units):
    // byte = lh*512 + l31*16  ->  ushort = lh*256 + l31*8
    const int lof = lh * 256 + l31 * 8;

    f32x16 zero16 = {0.f,0.f,0.f,0.f,0.f,0.f,0.f,0.f,0.f,0.f,0.f,0.f,0.f,0.f,0.f,0.f};
    f32x16 acc[4][4];
#pragma unroll
    for (int i = 0; i < 4; ++i)
#pragma unroll
        for (int j = 0; j < 4; ++j) acc[i][j] = zero16;

    float ian[4];
#pragma unroll
    for (int nt = 0; nt < 4; ++nt) ian[nt] = inv_an[c0 + wn * 128 + nt * 32 + l31];

    // prologue: stage chunk 0 -> buf 0
#pragma unroll
    for (int rb = 0; rb < 8; ++rb)
        async_load16(gp[rb], myseg + rb * 512);

    for (int kc = 0; kc < 64; ++kc) {
        __syncthreads();  // vmcnt drain: chunk kc staged; prev compute done
        const int cur = (kc & 1) * 16384;
        if (kc < 63) {
            const int nxt = ((kc + 1) & 1) * 16384;
            const int gofs = (kc + 1) * 32;  // bytes: 16 k * 2B
#pragma unroll
            for (int rb = 0; rb < 8; ++rb)
                async_load16(gp[rb] + gofs, myseg + nxt + rb * 512);
        }

        bf16x8 ph[4], pl[4], ah[4], al[4];
#pragma unroll
        for (int t = 0; t < 4; ++t) {
            const int prb = wm * 4 + t;
            const int arb = wn * 4 + t;
            ph[t] = *(const bf16x8*)(lds + cur + 0 * 4096 + prb * 512 + lof);
            ah[t] = *(const bf16x8*)(lds + cur + 2 * 4096 + arb * 512 + lof);
            pl[t] = *(const bf16x8*)(lds + cur + 1 * 4096 + prb * 512 + lof);
            al[t] = *(const bf16x8*)(lds + cur + 3 * 4096 + arb * 512 + lof);
        }
#pragma unroll
        for (int mt = 0; mt < 4; ++mt)
#pragma unroll
            for (int nt = 0; nt < 4; ++nt)
                acc[mt][nt] = __builtin_amdgcn_mfma_f32_32x32x16_bf16(ph[mt], ah[nt], acc[mt][nt], 0, 0, 0);
#pragma unroll
        for (int mt = 0; mt < 4; ++mt)
#pragma unroll
            for (int nt = 0; nt < 4; ++nt)
                acc[mt][nt] = __builtin_amdgcn_mfma_f32_32x32x16_bf16(ph[mt], al[nt], acc[mt][nt], 0, 0, 0);
#pragma unroll
        for (int mt = 0; mt < 4; ++mt)
#pragma unroll
            for (int nt = 0; nt < 4; ++nt)
                acc[mt][nt] = __builtin_amdgcn_mfma_f32_32x32x16_bf16(pl[mt], ah[nt], acc[mt][nt], 0, 0, 0);
    }

    // ---- epilogue ----
    // 32x32 C/D layout (m74/m101): col = lane&31, row = (reg&3)+8*(reg>>2)+4*(lane>>5)
#pragma unroll
    for (int mt = 0; mt < 4; ++mt)
#pragma unroll
        for (int reg = 0; reg < 16; ++reg) {
            const int row = r0 + wm * 128 + mt * 32 + (reg & 3) + 8 * (reg >> 2) + 4 * lh;
            u64 best = 0ULL;
#pragma unroll
            for (int nt = 0; nt < 4; ++nt) {
                const int col = c0 + wn * 128 + nt * 32 + l31;
                const float v = acc[mt][nt][reg] * ian[nt];
                const u64 p = ((u64)fkey(v) << 32) | (unsigned int)(~col);
                best = best > p ? best : p;
            }
#pragma unroll
            for (int m = 1; m <= 16; m <<= 1) {
                const u64 o = shfl_xor_u64(best, m);
                best = best > o ? best : o;
            }
            if (l31 == 0) atomicMax(&packed[row], best);
        }
}

// ---------------- fallback fp32 path (proven R1) ----------------
__global__ __launch_bounds__(256) void norms_kernel(const float* __restrict__ x,
                                                    float* __restrict__ inv_an,
                                                    u64* __restrict__ packed) {
    int gid  = blockIdx.x * 256 + threadIdx.x;
    int j    = gid >> 6;
    int lane = threadIdx.x & 63;
    if (gid < NROWS) packed[gid] = 0ULL;
    const float4* a = (const float4*)(x + (size_t)j * XSTR + DDIM);
    float s = 0.0f;
#pragma unroll
    for (int i = 0; i < 4; ++i) {
        float4 v = a[lane + i * 64];
        s += v.x * v.x + v.y * v.y + v.z * v.z + v.w * v.w;
    }
#pragma unroll
    for (int off = 32; off > 0; off >>= 1) s += __shfl_down(s, off, 64);
    if (lane == 0) inv_an[j] = 1.0f / sqrtf(s);
}

__global__ __launch_bounds__(256) void gemm_argmax_kernel(const float* __restrict__ x,
                                                          const float* __restrict__ inv_an,
                                                          u64* __restrict__ packed) {
    __shared__ __align__(16) float Pt[16][128];
    __shared__ __align__(16) float At[16][128];
    const int r0 = blockIdx.x * 128;
    const int c0 = blockIdx.y * 128;
    const int t = threadIdx.x;
    const int tx = t & 15;
    const int ty = t >> 4;
    const int srow = t >> 1;
    const int skq = (t & 1) * 8;
    float acc[8][8];
#pragma unroll
    for (int r = 0; r < 8; ++r)
#pragma unroll
        for (int c = 0; c < 8; ++c) acc[r][c] = 0.0f;
    const float* gp = x + (size_t)(r0 + srow) * XSTR + skq;
    const float* ga = x + (size_t)(c0 + srow) * XSTR + DDIM + skq;
    for (int k0 = 0; k0 < DDIM; k0 += 16) {
        __syncthreads();
        float4 p0 = *(const float4*)(gp + k0);
        float4 p1 = *(const float4*)(gp + k0 + 4);
        float4 a0 = *(const float4*)(ga + k0);
        float4 a1 = *(const float4*)(ga + k0 + 4);
        Pt[skq + 0][srow] = p0.x; Pt[skq + 1][srow] = p0.y;
        Pt[skq + 2][srow] = p0.z; Pt[skq + 3][srow] = p0.w;
        Pt[skq + 4][srow] = p1.x; Pt[skq + 5][srow] = p1.y;
        Pt[skq + 6][srow] = p1.z; Pt[skq + 7][srow] = p1.w;
        At[skq + 0][srow] = a0.x; At[skq + 1][srow] = a0.y;
        At[skq + 2][srow] = a0.z; At[skq + 3][srow] = a0.w;
        At[skq + 4][srow] = a1.x; At[skq + 5][srow] = a1.y;
        At[skq + 6][srow] = a1.z; At[skq + 7][srow] = a1.w;
        __syncthreads();
#pragma unroll
        for (int kk = 0; kk < 16; ++kk) {
            float pr[8], ar[8];
            *(float4*)&pr[0] = *(const float4*)&Pt[kk][ty * 8];
            *(float4*)&pr[4] = *(const float4*)&Pt[kk][ty * 8 + 4];
            *(float4*)&ar[0] = *(const float4*)&At[kk][tx * 8];
            *(float4*)&ar[4] = *(const float4*)&At[kk][tx * 8 + 4];
#pragma unroll
            for (int r = 0; r < 8; ++r)
#pragma unroll
                for (int c = 0; c < 8; ++c) acc[r][c] += pr[r] * ar[c];
        }
    }
    float ian[8];
#pragma unroll
    for (int c = 0; c < 8; ++c) ian[c] = inv_an[c0 + tx * 8 + c];
#pragma unroll
    for (int r = 0; r < 8; ++r) {
        int row = r0 + ty * 8 + r;
        u64 best = 0ULL;
#pragma unroll
        for (int c = 0; c < 8; ++c) {
            int col = c0 + tx * 8 + c;
            float v = acc[r][c] * ian[c];
            u64 p = ((u64)fkey(v) << 32) | (unsigned int)(~col);
            best = best > p ? best : p;
        }
#pragma unroll
        for (int m = 1; m <= 8; m <<= 1) {
            u64 o = shfl_xor_u64(best, m);
            best = best > o ? best : o;
        }
        if (tx == 0) atomicMax(&packed[row], best);
    }
}

// ---------------- finalize ----------------
__global__ __launch_bounds__(256) void finalize_kernel(const u64* __restrict__ packed,
                                                       float* __restrict__ out) {
    __shared__ int cnt_s;
    int t = threadIdx.x;
    if (t == 0) cnt_s = 0;
    __syncthreads();
    int c = 0;
    for (int r = t; r < NROWS; r += 256) {
        unsigned int col = ~(unsigned int)(packed[r] & 0xFFFFFFFFULL);
        c += (col == (unsigned int)r) ? 1 : 0;
    }
#pragma unroll
    for (int off = 32; off > 0; off >>= 1) c += __shfl_down(c, off, 64);
    if ((t & 63) == 0) atomicAdd(&cnt_s, c);
    __syncthreads();
    if (t == 0) {
        out[0] = 1.0f;
        out[1] = 100.0f * (float)cnt_s / (float)NROWS;
    }
}

extern "C" void kernel_launch(void* const* d_in, const int* in_sizes, int n_in,
                              void* d_out, int out_size, void* d_ws, size_t ws_size,
                              hipStream_t stream) {
    (void)in_sizes; (void)n_in; (void)out_size;
    const float* x = (const float*)d_in[0];
    float* out = (float*)d_out;

    if (ws_size >= (size_t)WS_NEED) {
        char* ws = (char*)d_ws;
        unsigned short* Phi = (unsigned short*)(ws + PHI_OFF);
        unsigned short* Plo = (unsigned short*)(ws + PLO_OFF);
        unsigned short* Ahi = (unsigned short*)(ws + AHI_OFF);
        unsigned short* Alo = (unsigned short*)(ws + ALO_OFF);
        float* inv_an = (float*)(ws + INV_OFF);
        u64* packed = (u64*)(ws + PCK_OFF);

        prep_kernel<<<NROWS, 256, 0, stream>>>(x, Phi, Plo, Ahi, Alo, inv_an, packed);
        dim3 grid(NROWS / 256, NROWS / 256);
        mfma_gemm_argmax<<<grid, 256, 0, stream>>>(Phi, Plo, Ahi, Alo, inv_an, packed);
        finalize_kernel<<<1, 256, 0, stream>>>(packed, out);
    } else {
        float* inv_an = (float*)d_ws;
        u64* packed = (u64*)((char*)d_ws + NROWS * sizeof(float));
        norms_kernel<<<NROWS / 4, 256, 0, stream>>>(x, inv_an, packed);
        dim3 grid(NROWS / 128, NROWS / 128);
        gemm_argmax_kernel<<<grid, 128 * 128 / 64, 0, stream>>>(x, inv_an, packed);
        finalize_kernel<<<1, 256, 0, stream>>>(packed, out);
    }
}